// Round 3
// baseline (281.505 us; speedup 1.0000x reference)
//
#include <hip/hip_runtime.h>
#include <hip/hip_cooperative_groups.h>
#include <math.h>

namespace cg = cooperative_groups;

#define V 50257
#define H 1024
#define NB 1024           // grid blocks (4/CU on 256 CUs)
#define NWAVES (NB * 4)   // fc waves

// ---------------------------------------------------------------------------
// Single persistent cooperative kernel:
//   Phase A: LSTM step (block k = hidden unit k)
//   grid.sync()
//   Phase B: FC matvec + per-wave online log-sum-exp -> partials[NB]
//   grid.sync()
//   Phase C: redundant merge of partials per block + normalize logits slice
// ---------------------------------------------------------------------------
__global__ __launch_bounds__(256) void decoder_kernel(
    const int* __restrict__ x,
    const float* __restrict__ hidden,
    const float* __restrict__ cell,
    const float* __restrict__ emb,
    const float* __restrict__ w_ih,
    const float* __restrict__ w_hh,
    const float* __restrict__ b_ih,
    const float* __restrict__ b_hh,
    const float* __restrict__ fc_w,
    const float* __restrict__ fc_b,
    float* __restrict__ out,
    float* __restrict__ logits,
    float2* __restrict__ partials)
{
    const int b = blockIdx.x;
    const int t = threadIdx.x;
    const int wave = t >> 6, lane = t & 63;

    __shared__ float  redA[8][4];
    __shared__ float2 pm[4];
    __shared__ float  subs;

    // ---------------- Phase A: LSTM for hidden unit k = b ----------------
    {
        const int k = b;
        const float* e = emb + (size_t)x[0] * H;
        const int idx = t * 4;  // 256 * 4 = 1024 = H
        const float4 ev = *(const float4*)(e + idx);
        const float4 hv = *(const float4*)(hidden + idx);

        float p[8];
#pragma unroll
        for (int g = 0; g < 4; ++g) {
            const float4 wi = *(const float4*)(w_ih + (size_t)(g * H + k) * H + idx);
            const float4 wh = *(const float4*)(w_hh + (size_t)(g * H + k) * H + idx);
            p[2 * g]     = wi.x * ev.x + wi.y * ev.y + wi.z * ev.z + wi.w * ev.w;
            p[2 * g + 1] = wh.x * hv.x + wh.y * hv.y + wh.z * hv.z + wh.w * hv.w;
        }
#pragma unroll
        for (int j = 0; j < 8; ++j) {
#pragma unroll
            for (int off = 32; off; off >>= 1)
                p[j] += __shfl_down(p[j], off, 64);
        }
        if (lane == 0) {
#pragma unroll
            for (int j = 0; j < 8; ++j) redA[j][wave] = p[j];
        }
        __syncthreads();
        if (t == 0) {
            float s[8];
#pragma unroll
            for (int j = 0; j < 8; ++j)
                s[j] = redA[j][0] + redA[j][1] + redA[j][2] + redA[j][3];
            const float gi = s[0] + s[1] + b_ih[k]         + b_hh[k];
            const float gf = s[2] + s[3] + b_ih[H + k]     + b_hh[H + k];
            const float gg = s[4] + s[5] + b_ih[2 * H + k] + b_hh[2 * H + k];
            const float go = s[6] + s[7] + b_ih[3 * H + k] + b_hh[3 * H + k];

            const float i_g = 1.0f / (1.0f + expf(-gi));
            const float f_g = 1.0f / (1.0f + expf(-gf));
            const float g_g = tanhf(gg);
            const float o_g = 1.0f / (1.0f + expf(-go));

            const float c_new = f_g * cell[k] + i_g * g_g;
            const float h_new = o_g * tanhf(c_new);

            out[V + k]     = h_new;
            out[V + H + k] = c_new;
            __threadfence();
        }
    }

    cg::this_grid().sync();

    // ---------------- Phase B: FC matvec + online LSE ----------------
    {
        const float* __restrict__ h_new = out + V;
        const int wid = b * 4 + wave;

        float4 hv[4];
#pragma unroll
        for (int it = 0; it < 4; ++it)
            hv[it] = *(const float4*)(h_new + (it * 64 + lane) * 4);

        float m = -INFINITY, s = 0.0f;

        for (int v = wid; v < V; v += NWAVES) {
            const float* row = fc_w + (size_t)v * H;
            float acc = 0.0f;
#pragma unroll
            for (int it = 0; it < 4; ++it) {
                const float4 w = *(const float4*)(row + (it * 64 + lane) * 4);
                acc += w.x * hv[it].x + w.y * hv[it].y + w.z * hv[it].z + w.w * hv[it].w;
            }
#pragma unroll
            for (int off = 1; off < 64; off <<= 1)
                acc += __shfl_xor(acc, off, 64);
            acc += fc_b[v];
            if (lane == 0) logits[v] = acc;

            const float nm = fmaxf(m, acc);
            s = s * __expf(m - nm) + __expf(acc - nm);
            m = nm;
        }

        if (lane == 0) pm[wave] = make_float2(m, s);
        __syncthreads();
        if (t == 0) {
            float M = pm[0].x, S = pm[0].y;
#pragma unroll
            for (int i = 1; i < 4; ++i) {
                const float m2 = pm[i].x, s2 = pm[i].y;
                const float nM = fmaxf(M, m2);
                S = S * __expf(M - nM) + s2 * __expf(m2 - nM);
                M = nM;
            }
            partials[b] = make_float2(M, S);
            __threadfence();
        }
    }

    cg::this_grid().sync();

    // ---------------- Phase C: merge partials + normalize ----------------
    {
        float m = -INFINITY, s = 0.0f;
#pragma unroll
        for (int i = 0; i < 4; ++i) {
            const float2 p = partials[t * 4 + i];  // 256 threads * 4 = NB
            const float nm = fmaxf(m, p.x);
            s = s * __expf(m - nm) + p.y * __expf(p.x - nm);
            m = nm;
        }
#pragma unroll
        for (int off = 1; off < 64; off <<= 1) {
            const float om = __shfl_xor(m, off, 64);
            const float os = __shfl_xor(s, off, 64);
            const float nm = fmaxf(m, om);
            s = s * __expf(m - nm) + os * __expf(om - nm);
            m = nm;
        }
        if (lane == 0) pm[wave] = make_float2(m, s);
        __syncthreads();
        if (t == 0) {
            float M = pm[0].x, S = pm[0].y;
#pragma unroll
            for (int i = 1; i < 4; ++i) {
                const float nm2 = fmaxf(M, pm[i].x);
                S = S * __expf(M - nm2) + pm[i].y * __expf(pm[i].x - nm2);
                M = nm2;
            }
            subs = M + logf(S);
        }
        __syncthreads();
        const float sub = subs;

        // block b normalizes logits [b*50, b*50+50) ∩ [0,V)
        const int v = b * 50 + t;
        if (t < 50 && v < V) out[v] = logits[v] - sub;
    }
}

extern "C" void kernel_launch(void* const* d_in, const int* in_sizes, int n_in,
                              void* d_out, int out_size, void* d_ws, size_t ws_size,
                              hipStream_t stream)
{
    const int*   x      = (const int*)  d_in[0];
    const float* hidden = (const float*)d_in[1];
    const float* cell   = (const float*)d_in[2];
    const float* emb    = (const float*)d_in[3];
    const float* w_ih   = (const float*)d_in[4];
    const float* w_hh   = (const float*)d_in[5];
    const float* b_ih   = (const float*)d_in[6];
    const float* b_hh   = (const float*)d_in[7];
    const float* fc_w   = (const float*)d_in[8];
    const float* fc_b   = (const float*)d_in[9];
    float* out = (float*)d_out;

    float*  logits   = (float*)d_ws;                           // V floats
    float2* partials = (float2*)(logits + ((V + 255) & ~255)); // NB float2

    void* args[] = {
        (void*)&x, (void*)&hidden, (void*)&cell, (void*)&emb,
        (void*)&w_ih, (void*)&w_hh, (void*)&b_ih, (void*)&b_hh,
        (void*)&fc_w, (void*)&fc_b, (void*)&out, (void*)&logits,
        (void*)&partials
    };
    hipLaunchCooperativeKernel((const void*)decoder_kernel,
                               dim3(NB), dim3(256), args, 0, stream);
}

// Round 4
// 45.657 us; speedup vs baseline: 6.1656x; 6.1656x over previous
//
#include <hip/hip_runtime.h>
#include <hip/hip_bf16.h>
#include <math.h>

#define V 50257
#define H 1024
#define NB_FC 1024            // fc blocks; 4 waves each -> 4096 waves
#define NWAVES (NB_FC * 4)

// ---------------------------------------------------------------------------
// Kernel 1: fused LSTM step.
// Block k (0..H-1) computes gate rows {k, H+k, 2H+k, 3H+k} of
// gates = w_ih @ e + b_ih + w_hh @ h + b_hh, applies nonlinearities, and
// writes h_new -> out[V+k], c_new -> out[V+H+k].
// ---------------------------------------------------------------------------
__global__ __launch_bounds__(256) void lstm_kernel(
    const int* __restrict__ x,
    const float* __restrict__ hidden,
    const float* __restrict__ cell,
    const float* __restrict__ emb,
    const float* __restrict__ w_ih,
    const float* __restrict__ w_hh,
    const float* __restrict__ b_ih,
    const float* __restrict__ b_hh,
    float* __restrict__ out)
{
    const int k = blockIdx.x;
    const int t = threadIdx.x;
    const float* e = emb + (size_t)x[0] * H;

    const int idx = t * 4;  // 256 threads * 4 = 1024 = H
    const float4 ev = *(const float4*)(e + idx);
    const float4 hv = *(const float4*)(hidden + idx);

    float p[8];
#pragma unroll
    for (int g = 0; g < 4; ++g) {
        const float4 wi = *(const float4*)(w_ih + (size_t)(g * H + k) * H + idx);
        const float4 wh = *(const float4*)(w_hh + (size_t)(g * H + k) * H + idx);
        p[2 * g]     = wi.x * ev.x + wi.y * ev.y + wi.z * ev.z + wi.w * ev.w;
        p[2 * g + 1] = wh.x * hv.x + wh.y * hv.y + wh.z * hv.z + wh.w * hv.w;
    }

#pragma unroll
    for (int j = 0; j < 8; ++j) {
#pragma unroll
        for (int off = 32; off; off >>= 1)
            p[j] += __shfl_down(p[j], off, 64);
    }

    __shared__ float red[8][4];
    const int wave = t >> 6, lane = t & 63;
    if (lane == 0) {
#pragma unroll
        for (int j = 0; j < 8; ++j) red[j][wave] = p[j];
    }
    __syncthreads();

    if (t == 0) {
        float s[8];
#pragma unroll
        for (int j = 0; j < 8; ++j)
            s[j] = red[j][0] + red[j][1] + red[j][2] + red[j][3];
        const float gi = s[0] + s[1] + b_ih[k]         + b_hh[k];
        const float gf = s[2] + s[3] + b_ih[H + k]     + b_hh[H + k];
        const float gg = s[4] + s[5] + b_ih[2 * H + k] + b_hh[2 * H + k];
        const float go = s[6] + s[7] + b_ih[3 * H + k] + b_hh[3 * H + k];

        const float i_g = 1.0f / (1.0f + expf(-gi));
        const float f_g = 1.0f / (1.0f + expf(-gf));
        const float g_g = tanhf(gg);
        const float o_g = 1.0f / (1.0f + expf(-go));

        const float c_new = f_g * cell[k] + i_g * g_g;
        const float h_new = o_g * tanhf(c_new);

        out[V + k]     = h_new;
        out[V + H + k] = c_new;
    }
}

// ---------------------------------------------------------------------------
// Kernel 2: FC matvec + fused online log-sum-exp partials.
// 4096 waves grid-stride over vocab rows, TWO rows per iteration (8 float4
// loads in flight per lane). h_new hoisted to registers. Block merges 4 wave
// (m,s) partials -> partials[blockIdx].
// ---------------------------------------------------------------------------
__global__ __launch_bounds__(256) void fc_lse_kernel(
    const float* __restrict__ fc_w,
    const float* __restrict__ fc_b,
    const float* __restrict__ h_new,   // = out + V
    float* __restrict__ logits,
    float2* __restrict__ partials)
{
    const int wave = threadIdx.x >> 6;
    const int lane = threadIdx.x & 63;
    const int wid = blockIdx.x * 4 + wave;

    float4 hv[4];
#pragma unroll
    for (int it = 0; it < 4; ++it)
        hv[it] = *(const float4*)(h_new + (it * 64 + lane) * 4);

    float m = -INFINITY, s = 0.0f;

    for (int v = wid * 2; v < V; v += NWAVES * 2) {
        const float* r0 = fc_w + (size_t)v * H;
        const bool two = (v + 1 < V);
        const float* r1 = r0 + (two ? H : 0);

        float a0 = 0.0f, a1 = 0.0f;
#pragma unroll
        for (int it = 0; it < 4; ++it) {
            const int off = (it * 64 + lane) * 4;
            const float4 w0 = *(const float4*)(r0 + off);
            const float4 w1 = *(const float4*)(r1 + off);
            a0 += w0.x * hv[it].x + w0.y * hv[it].y + w0.z * hv[it].z + w0.w * hv[it].w;
            a1 += w1.x * hv[it].x + w1.y * hv[it].y + w1.z * hv[it].z + w1.w * hv[it].w;
        }
#pragma unroll
        for (int off = 1; off < 64; off <<= 1) {
            a0 += __shfl_xor(a0, off, 64);
            a1 += __shfl_xor(a1, off, 64);
        }
        a0 += fc_b[v];
        a1 = two ? (a1 + fc_b[v + 1]) : -INFINITY;

        if (lane == 0) {
            logits[v] = a0;
            if (two) logits[v + 1] = a1;
        }

        const float nm = fmaxf(m, fmaxf(a0, a1));
        s = s * __expf(m - nm) + __expf(a0 - nm) + __expf(a1 - nm);
        m = nm;
    }

    __shared__ float2 pm[4];
    if (lane == 0) pm[wave] = make_float2(m, s);
    __syncthreads();
    if (threadIdx.x == 0) {
        float M = pm[0].x, S = pm[0].y;
#pragma unroll
        for (int i = 1; i < 4; ++i) {
            const float m2 = pm[i].x, s2 = pm[i].y;
            const float nM = fmaxf(M, m2);
            S = S * __expf(M - nM) + s2 * __expf(m2 - nM);
            M = nM;
        }
        partials[blockIdx.x] = make_float2(M, S);
    }
}

// ---------------------------------------------------------------------------
// Kernel 3: each block redundantly merges the 1024 (m,s) partials (identical
// deterministic result), then normalizes its slice of the logits (float4 IO).
// Grid: ceil(V/1024) blocks of 256 threads; 4 outputs per thread.
// ---------------------------------------------------------------------------
__global__ __launch_bounds__(256) void logp_kernel(
    const float* __restrict__ logits,
    const float2* __restrict__ partials,
    float* __restrict__ out)
{
    const int t = threadIdx.x;
    const int lane = t & 63;
    const int wave = t >> 6;

    float m = -INFINITY, s = 0.0f;
#pragma unroll
    for (int i = 0; i < 4; ++i) {
        const float2 p = partials[t * 4 + i];
        const float nm = fmaxf(m, p.x);
        s = s * __expf(m - nm) + p.y * __expf(p.x - nm);
        m = nm;
    }
#pragma unroll
    for (int off = 1; off < 64; off <<= 1) {
        const float om = __shfl_xor(m, off, 64);
        const float os = __shfl_xor(s, off, 64);
        const float nm = fmaxf(m, om);
        s = s * __expf(m - nm) + os * __expf(om - nm);
        m = nm;
    }
    __shared__ float2 red[4];
    __shared__ float sub_s;
    if (lane == 0) red[wave] = make_float2(m, s);
    __syncthreads();
    if (t == 0) {
        float M = red[0].x, S = red[0].y;
#pragma unroll
        for (int i = 1; i < 4; ++i) {
            const float nm2 = fmaxf(M, red[i].x);
            S = S * __expf(M - nm2) + red[i].y * __expf(red[i].x - nm2);
            M = nm2;
        }
        sub_s = M + logf(S);
    }
    __syncthreads();
    const float sub = sub_s;

    const int base = (blockIdx.x * 256 + t) * 4;
    if (base + 3 < V) {
        const float4 l = *(const float4*)(logits + base);
        float4 o;
        o.x = l.x - sub; o.y = l.y - sub; o.z = l.z - sub; o.w = l.w - sub;
        *(float4*)(out + base) = o;
    } else {
#pragma unroll
        for (int j = 0; j < 4; ++j) {
            const int v = base + j;
            if (v < V) out[v] = logits[v] - sub;
        }
    }
}

extern "C" void kernel_launch(void* const* d_in, const int* in_sizes, int n_in,
                              void* d_out, int out_size, void* d_ws, size_t ws_size,
                              hipStream_t stream)
{
    const int*   x      = (const int*)  d_in[0];
    const float* hidden = (const float*)d_in[1];
    const float* cell   = (const float*)d_in[2];
    const float* emb    = (const float*)d_in[3];
    const float* w_ih   = (const float*)d_in[4];
    const float* w_hh   = (const float*)d_in[5];
    const float* b_ih   = (const float*)d_in[6];
    const float* b_hh   = (const float*)d_in[7];
    const float* fc_w   = (const float*)d_in[8];
    const float* fc_b   = (const float*)d_in[9];
    float* out = (float*)d_out;

    float*  logits   = (float*)d_ws;                           // V floats
    float2* partials = (float2*)(logits + ((V + 255) & ~255)); // NB_FC float2

    // 1) LSTM step -> out[V .. V+2H)
    lstm_kernel<<<H, 256, 0, stream>>>(x, hidden, cell, emb, w_ih, w_hh,
                                       b_ih, b_hh, out);
    // 2) FC matvec + LSE partials
    fc_lse_kernel<<<NB_FC, 256, 0, stream>>>(fc_w, fc_b, out + V, logits, partials);
    // 3) merge partials (redundant per block) + normalize -> out[0 .. V)
    logp_kernel<<<(V + 1023) / 1024, 256, 0, stream>>>(logits, partials, out);
}